// Round 1
// baseline (1661.264 us; speedup 1.0000x reference)
//
#include <hip/hip_runtime.h>

typedef float floatx4 __attribute__((ext_vector_type(4)));
typedef short short8 __attribute__((ext_vector_type(8)));
typedef unsigned short ushort4v __attribute__((ext_vector_type(4)));

#define H 768
#define NMENT 4096
#define TOTALP 131072
#define MAXK 64
#define LDA 776   // bf16 row stride in LDS: 768 + 8 pad (keeps 16B align, breaks bank conflicts)

__device__ __forceinline__ unsigned short f32_to_bf16(float f) {
    unsigned int u = __builtin_bit_cast(unsigned int, f);
    u = u + 0x7FFFu + ((u >> 16) & 1u);   // round-to-nearest-even
    return (unsigned short)(u >> 16);
}

// K0: W1 [1536 x 768] row-major -> BtA[n][k] = W1[k][n] (k<768), BtB[n][k] = W1[768+k][n], bf16
__global__ void k0_transpose(const float* __restrict__ W1,
                             unsigned short* __restrict__ BtA,
                             unsigned short* __restrict__ BtB) {
    __shared__ float tile[32][33];
    const int k0 = blockIdx.x * 32;   // 0..1535
    const int n0 = blockIdx.y * 32;   // 0..767
    const int tx = threadIdx.x;       // 0..31
    const int ty = threadIdx.y;       // 0..7
#pragma unroll
    for (int i = 0; i < 4; ++i)
        tile[ty + i * 8][tx] = W1[(k0 + ty + i * 8) * H + n0 + tx];
    __syncthreads();
    unsigned short* dst = (k0 < H) ? BtA : BtB;
    const int kb = (k0 >= H) ? (k0 - H) : k0;
#pragma unroll
    for (int i = 0; i < 4; ++i) {
        const int n = n0 + ty + i * 8;
        dst[n * H + kb + tx] = f32_to_bf16(tile[tx][ty + i * 8]);
    }
}

// K3: out[n][j] = 0.5*faiss[n][j] for j<64, nota for j==64
__global__ void k3_init_out(const float* __restrict__ faiss,
                            const float* __restrict__ nota,
                            float* __restrict__ out) {
    const int i = blockIdx.x * 256 + threadIdx.x;
    if (i < NMENT * (MAXK + 1)) {
        const int n = i / (MAXK + 1);
        const int j = i - n * (MAXK + 1);
        out[i] = (j < MAXK) ? 0.5f * faiss[n * MAXK + j] : nota[0];
    }
}

// K1: M[4096 x 768] = mention_embs @ W1a + b1  (bf16 MFMA, fp32 out)
__global__ __launch_bounds__(512, 2)
void k1_mention_gemm(const float* __restrict__ ment,
                     const unsigned short* __restrict__ BtA,
                     const float* __restrict__ b1,
                     float* __restrict__ M) {
    __shared__ unsigned short ldsA[64 * LDA];
    __shared__ float ldsb1[H];
    const int tid = threadIdx.x;
    const int r0 = blockIdx.x * 64;

#pragma unroll
    for (int i = 0; i < 24; ++i) {                 // 64 rows * 192 float4 = 12288 / 512
        int idx = tid + i * 512;
        int row = idx / 192;
        int c4 = idx - row * 192;
        float4 v = ((const float4*)(ment + (long)(r0 + row) * H))[c4];
        ushort4v u;
        u.x = f32_to_bf16(v.x); u.y = f32_to_bf16(v.y);
        u.z = f32_to_bf16(v.z); u.w = f32_to_bf16(v.w);
        *(ushort4v*)(&ldsA[row * LDA + c4 * 4]) = u;
    }
    for (int i = tid; i < H; i += 512) ldsb1[i] = b1[i];
    __syncthreads();

    const int lane = tid & 63;
    const int wave = tid >> 6;          // 8 waves
    const int strip = wave >> 1;        // 4 strips of 16 rows
    const int nhalf = wave & 1;         // n 64-col half of each 128-col n-tile
    const int l15 = lane & 15;
    const int quad = lane >> 4;

    const unsigned short* abase = &ldsA[(strip * 16 + l15) * LDA + quad * 8];
    const unsigned short* bbase = BtA + (nhalf * 64 + l15) * H + quad * 8;

    for (int nt = 0; nt < 6; ++nt) {
        floatx4 acc[4];
#pragma unroll
        for (int s = 0; s < 4; ++s) acc[s] = floatx4{0.f, 0.f, 0.f, 0.f};
        for (int ks = 0; ks < 24; ++ks) {
            short8 a = *(const short8*)(abase + ks * 32);
#pragma unroll
            for (int s = 0; s < 4; ++s) {
                short8 b = *(const short8*)(bbase + (nt * 128 + s * 16) * H + ks * 32);
                acc[s] = __builtin_amdgcn_mfma_f32_16x16x32_bf16(a, b, acc[s], 0, 0, 0);
            }
        }
#pragma unroll
        for (int s = 0; s < 4; ++s) {
            const int n = nt * 128 + nhalf * 64 + s * 16 + l15;
            const float bb = ldsb1[n];
#pragma unroll
            for (int r = 0; r < 4; ++r) {
                const int row = r0 + strip * 16 + quad * 4 + r;
                M[row * H + n] = acc[s][r] + bb;
            }
        }
    }
}

// K2: fused candidate GEMM + M-gather + relu + dot(W2) + scatter into out
__global__ __launch_bounds__(512, 2)
void k2_fused(const float* __restrict__ cand,
              const unsigned short* __restrict__ BtB,
              const float* __restrict__ M,
              const float* __restrict__ W2,
              const float* __restrict__ b2,
              const float* __restrict__ faiss,
              const int* __restrict__ mention_idx,
              const int* __restrict__ col_idx,
              float* __restrict__ out) {
    __shared__ unsigned short ldsA[64 * LDA];
    __shared__ float ldsW2[H];
    __shared__ float scoreBuf[128];    // [row64][nhalf]

    const int tid = threadIdx.x;
    const int t0 = blockIdx.x * 64;

#pragma unroll
    for (int i = 0; i < 24; ++i) {
        int idx = tid + i * 512;
        int row = idx / 192;
        int c4 = idx - row * 192;
        float4 v = ((const float4*)(cand + (long)(t0 + row) * H))[c4];
        ushort4v u;
        u.x = f32_to_bf16(v.x); u.y = f32_to_bf16(v.y);
        u.z = f32_to_bf16(v.z); u.w = f32_to_bf16(v.w);
        *(ushort4v*)(&ldsA[row * LDA + c4 * 4]) = u;
    }
    for (int i = tid; i < H; i += 512) ldsW2[i] = W2[i];
    __syncthreads();

    const int lane = tid & 63;
    const int wave = tid >> 6;
    const int strip = wave >> 1;
    const int nhalf = wave & 1;
    const int l15 = lane & 15;
    const int quad = lane >> 4;

    int mrow[4];
#pragma unroll
    for (int r = 0; r < 4; ++r)
        mrow[r] = mention_idx[t0 + strip * 16 + quad * 4 + r];

    float sc[4] = {0.f, 0.f, 0.f, 0.f};
    const unsigned short* abase = &ldsA[(strip * 16 + l15) * LDA + quad * 8];
    const unsigned short* bbase = BtB + (nhalf * 64 + l15) * H + quad * 8;

    for (int nt = 0; nt < 6; ++nt) {
        floatx4 acc[4];
#pragma unroll
        for (int s = 0; s < 4; ++s) acc[s] = floatx4{0.f, 0.f, 0.f, 0.f};
        for (int ks = 0; ks < 24; ++ks) {
            short8 a = *(const short8*)(abase + ks * 32);
#pragma unroll
            for (int s = 0; s < 4; ++s) {
                short8 b = *(const short8*)(bbase + (nt * 128 + s * 16) * H + ks * 32);
                acc[s] = __builtin_amdgcn_mfma_f32_16x16x32_bf16(a, b, acc[s], 0, 0, 0);
            }
        }
        // epilogue for this 128-col n-tile: + M, relu, dot W2
#pragma unroll
        for (int s = 0; s < 4; ++s) {
            const int n = nt * 128 + nhalf * 64 + s * 16 + l15;
            const float w2v = ldsW2[n];
#pragma unroll
            for (int r = 0; r < 4; ++r) {
                float v = acc[s][r] + M[mrow[r] * H + n];
                v = fmaxf(v, 0.f);
                sc[r] = fmaf(v, w2v, sc[r]);
            }
        }
    }

    // reduce partial scores across the 16 lanes of each quad group
#pragma unroll
    for (int r = 0; r < 4; ++r) {
        float v = sc[r];
        v += __shfl_xor(v, 1, 64);
        v += __shfl_xor(v, 2, 64);
        v += __shfl_xor(v, 4, 64);
        v += __shfl_xor(v, 8, 64);
        if (l15 == 0) scoreBuf[(strip * 16 + quad * 4 + r) * 2 + nhalf] = v;
    }
    __syncthreads();

    if (tid < 64) {
        const int t = t0 + tid;
        const int m = mention_idx[t];
        const int c = col_idx[t];
        out[m * (MAXK + 1) + c] =
            scoreBuf[tid * 2] + scoreBuf[tid * 2 + 1] + b2[0] + 0.5f * faiss[m * MAXK + c];
    }
}

extern "C" void kernel_launch(void* const* d_in, const int* in_sizes, int n_in,
                              void* d_out, int out_size, void* d_ws, size_t ws_size,
                              hipStream_t stream) {
    const float* ment  = (const float*)d_in[0];
    const float* cand  = (const float*)d_in[1];
    const float* W1    = (const float*)d_in[2];
    const float* b1    = (const float*)d_in[3];
    const float* W2    = (const float*)d_in[4];
    const float* b2    = (const float*)d_in[5];
    const float* faiss = (const float*)d_in[6];
    const float* nota  = (const float*)d_in[7];
    const int* mention_idx = (const int*)d_in[8];
    const int* col_idx = (const int*)d_in[9];
    float* out = (float*)d_out;

    // ws layout: BtA bf16 [768*768] | BtB bf16 [768*768] | M fp32 [4096*768]  (~14.3 MB)
    unsigned short* BtA = (unsigned short*)d_ws;
    unsigned short* BtB = BtA + H * H;
    float* M = (float*)(BtB + H * H);

    k0_transpose<<<dim3(48, 24), dim3(32, 8), 0, stream>>>(W1, BtA, BtB);
    k3_init_out<<<(NMENT * (MAXK + 1) + 255) / 256, 256, 0, stream>>>(faiss, nota, out);
    k1_mention_gemm<<<NMENT / 64, 512, 0, stream>>>(ment, BtA, b1, M);
    k2_fused<<<TOTALP / 64, 512, 0, stream>>>(cand, BtB, M, W2, b2, faiss,
                                              mention_idx, col_idx, out);
}

// Round 2
// 783.496 us; speedup vs baseline: 2.1203x; 2.1203x over previous
//
#include <hip/hip_runtime.h>

typedef float floatx4 __attribute__((ext_vector_type(4)));
typedef short short8 __attribute__((ext_vector_type(8)));

#define H 768
#define NMENT 4096
#define TOTALP 131072
#define MAXK 64
#define BM 256
#define BN 256
#define BK 64
#define LDA_S 72   // shorts per A row in LDS: 64 data + 8 pad (144B rows, 16B aligned, conflict-free)

__device__ __forceinline__ unsigned short f32_to_bf16(float f) {
    unsigned int u = __builtin_bit_cast(unsigned int, f);
    u = u + 0x7FFFu + ((u >> 16) & 1u);   // round-to-nearest-even
    return (unsigned short)(u >> 16);
}

__device__ __forceinline__ short8 pack8(float4 a, float4 b) {
    short8 r;
    r[0] = (short)f32_to_bf16(a.x); r[1] = (short)f32_to_bf16(a.y);
    r[2] = (short)f32_to_bf16(a.z); r[3] = (short)f32_to_bf16(a.w);
    r[4] = (short)f32_to_bf16(b.x); r[5] = (short)f32_to_bf16(b.y);
    r[6] = (short)f32_to_bf16(b.z); r[7] = (short)f32_to_bf16(b.w);
    return r;
}

__device__ __forceinline__ void glds16(const unsigned short* g, unsigned short* l) {
    __builtin_amdgcn_global_load_lds(
        (const __attribute__((address_space(1))) unsigned int*)g,
        (__attribute__((address_space(3))) unsigned int*)l, 16, 0, 0);
}

// K0: W1 [1536 x 768] row-major -> BtA[n][k] = W1[k][n] (k<768), BtB[n][k] = W1[768+k][n], bf16
__global__ void k0_transpose(const float* __restrict__ W1,
                             unsigned short* __restrict__ BtA,
                             unsigned short* __restrict__ BtB) {
    __shared__ float tile[32][33];
    const int k0 = blockIdx.x * 32;
    const int n0 = blockIdx.y * 32;
    const int tx = threadIdx.x;
    const int ty = threadIdx.y;
#pragma unroll
    for (int i = 0; i < 4; ++i)
        tile[ty + i * 8][tx] = W1[(k0 + ty + i * 8) * H + n0 + tx];
    __syncthreads();
    unsigned short* dst = (k0 < H) ? BtA : BtB;
    const int kb = (k0 >= H) ? (k0 - H) : k0;
#pragma unroll
    for (int i = 0; i < 4; ++i) {
        const int n = n0 + ty + i * 8;
        dst[n * H + kb + tx] = f32_to_bf16(tile[tx][ty + i * 8]);
    }
}

// K3: out[n][j] = 0.5*faiss[n][j] for j<64, nota for j==64 (b2 added by nsplit==0 k2 blocks)
__global__ void k3_init_out(const float* __restrict__ faiss,
                            const float* __restrict__ nota,
                            float* __restrict__ out) {
    const int i = blockIdx.x * 256 + threadIdx.x;
    if (i < NMENT * (MAXK + 1)) {
        const int n = i / (MAXK + 1);
        const int j = i - n * (MAXK + 1);
        out[i] = (j < MAXK) ? 0.5f * faiss[n * MAXK + j] : nota[0];
    }
}

// Core GEMM: C[t0..t0+255][n0..n0+255] = A(rows, fp32, cast bf16) @ Bt^T (bf16 [n][k])
// MODE 0: epilogue writes M = acc + b1  (outp = M, w2s holds b1 chunk)
// MODE 1: epilogue: h = acc + M[mention], relu, dot W2-chunk, reduce, atomicAdd to out
template<int MODE>
__global__ __launch_bounds__(1024, 4)
void gemm_core(const float* __restrict__ A, const unsigned short* __restrict__ Bt,
               const float* __restrict__ M, const float* __restrict__ W2,
               const float* __restrict__ b2, const int* __restrict__ mention_idx,
               const int* __restrict__ col_idx, const float* __restrict__ b1,
               float* __restrict__ outp) {
    __shared__ unsigned short ldsA[BM * LDA_S];  // 36864 B
    __shared__ unsigned short ldsB[BN * BK];     // 32768 B, XOR-swizzled chunks
    __shared__ float w2s[BN];                    // W2 chunk (MODE 1) or b1 chunk (MODE 0)
    __shared__ float scoreBuf[BM * 4];

    const int bid = blockIdx.x;
    int t_tile, nsplit;
    if (MODE == 1) {
        // group blocks so the 3 n-splits of a t-tile land on the same XCD (bid%8 round-robin)
        const int g = bid / 24, rr = bid % 24;
        t_tile = g * 8 + (rr & 7);
        nsplit = rr >> 3;
    } else {
        t_tile = bid % 16;
        nsplit = bid / 16;
    }
    const int t0 = t_tile * BM;
    const int n0 = nsplit * BN;

    const int tid = threadIdx.x;
    const int lane = tid & 63;
    const int w = tid >> 6;           // 16 waves: 4x4 grid of 64x64 wave tiles
    const int wm = w >> 2, wn = w & 3;
    const int l15 = lane & 15, quad = lane >> 4;

    if (tid < BN) w2s[tid] = (MODE == 1) ? W2[n0 + tid] : b1[n0 + tid];

    floatx4 acc[4][4];
#pragma unroll
    for (int mi = 0; mi < 4; ++mi)
#pragma unroll
        for (int ni = 0; ni < 4; ++ni)
            acc[mi][ni] = floatx4{0.f, 0.f, 0.f, 0.f};

    // A staging map: 4 threads per row, 16 floats (64B) each
    const int arow = tid >> 2;
    const int aseg = tid & 3;
    const float* agp = A + (size_t)(t0 + arow) * H + aseg * 16;
    unsigned short* alp = &ldsA[arow * LDA_S + aseg * 16];

    for (int kc = 0; kc < H; kc += BK) {
        // --- stage A: fp32 -> bf16, padded rows ---
        float4 v0 = *(const float4*)(agp + kc);
        float4 v1 = *(const float4*)(agp + kc + 4);
        float4 v2 = *(const float4*)(agp + kc + 8);
        float4 v3 = *(const float4*)(agp + kc + 12);
        *(short8*)(alp) = pack8(v0, v1);
        *(short8*)(alp + 8) = pack8(v2, v3);
        // --- stage B: global_load_lds 16B, XOR swizzle: slot c holds data chunk c^(row&7) ---
#pragma unroll
        for (int i = 0; i < 2; ++i) {
            const int br = w * 16 + i * 8;          // wave-uniform base row
            const int r = br + (lane >> 3);
            const int cd = (lane & 7) ^ (r & 7);    // data chunk for this slot
            glds16(Bt + (size_t)(n0 + r) * H + kc + cd * 8, &ldsB[br * BK]);
        }
        __syncthreads();
        // --- compute: 2 k32 steps, 16 MFMAs each ---
#pragma unroll
        for (int ks = 0; ks < 2; ++ks) {
            short8 a[4], b[4];
#pragma unroll
            for (int mi = 0; mi < 4; ++mi)
                a[mi] = *(const short8*)&ldsA[(wm * 64 + mi * 16 + l15) * LDA_S + ks * 32 + quad * 8];
#pragma unroll
            for (int ni = 0; ni < 4; ++ni) {
                const int nr = wn * 64 + ni * 16 + l15;
                const int slot = (quad + ks * 4) ^ (nr & 7);
                b[ni] = *(const short8*)&ldsB[nr * BK + slot * 8];
            }
#pragma unroll
            for (int mi = 0; mi < 4; ++mi)
#pragma unroll
                for (int ni = 0; ni < 4; ++ni)
                    acc[mi][ni] = __builtin_amdgcn_mfma_f32_16x16x32_bf16(a[mi], b[ni], acc[mi][ni], 0, 0, 0);
        }
        __syncthreads();
    }

    if (MODE == 0) {
        // write M = acc + b1
#pragma unroll
        for (int ni = 0; ni < 4; ++ni) {
            const int nl = wn * 64 + ni * 16 + l15;
            const float bv = w2s[nl];
#pragma unroll
            for (int mi = 0; mi < 4; ++mi)
#pragma unroll
                for (int r = 0; r < 4; ++r) {
                    const int row = t0 + wm * 64 + mi * 16 + quad * 4 + r;
                    outp[(size_t)row * H + n0 + nl] = acc[mi][ni][r] + bv;
                }
        }
    } else {
        // h = acc + M[mention]; relu; dot with W2 chunk; reduce; atomicAdd
#pragma unroll
        for (int mi = 0; mi < 4; ++mi) {
#pragma unroll
            for (int r = 0; r < 4; ++r) {
                const int rl = wm * 64 + mi * 16 + quad * 4 + r;
                const int m = mention_idx[t0 + rl];
                const float* Mrow = M + (size_t)m * H + n0;
                float s = 0.f;
#pragma unroll
                for (int ni = 0; ni < 4; ++ni) {
                    const int nl = wn * 64 + ni * 16 + l15;
                    const float v = acc[mi][ni][r] + Mrow[nl];
                    s = fmaf(fmaxf(v, 0.f), w2s[nl], s);
                }
                s += __shfl_xor(s, 1, 64);
                s += __shfl_xor(s, 2, 64);
                s += __shfl_xor(s, 4, 64);
                s += __shfl_xor(s, 8, 64);
                if (l15 == 0) scoreBuf[rl * 4 + wn] = s;
            }
        }
        __syncthreads();
        if (tid < BM) {
            const int t = t0 + tid;
            float tot = scoreBuf[tid * 4] + scoreBuf[tid * 4 + 1] +
                        scoreBuf[tid * 4 + 2] + scoreBuf[tid * 4 + 3];
            if (nsplit == 0) tot += b2[0];
            atomicAdd(&outp[(size_t)mention_idx[t] * (MAXK + 1) + col_idx[t]], tot);
        }
    }
}

extern "C" void kernel_launch(void* const* d_in, const int* in_sizes, int n_in,
                              void* d_out, int out_size, void* d_ws, size_t ws_size,
                              hipStream_t stream) {
    const float* ment  = (const float*)d_in[0];
    const float* cand  = (const float*)d_in[1];
    const float* W1    = (const float*)d_in[2];
    const float* b1    = (const float*)d_in[3];
    const float* W2    = (const float*)d_in[4];
    const float* b2    = (const float*)d_in[5];
    const float* faiss = (const float*)d_in[6];
    const float* nota  = (const float*)d_in[7];
    const int* mention_idx = (const int*)d_in[8];
    const int* col_idx = (const int*)d_in[9];
    float* out = (float*)d_out;

    // ws: BtA bf16 [768*768] | BtB bf16 [768*768] | M fp32 [4096*768]  (~14.9 MB)
    unsigned short* BtA = (unsigned short*)d_ws;
    unsigned short* BtB = BtA + H * H;
    float* M = (float*)(BtB + H * H);

    k0_transpose<<<dim3(48, 24), dim3(32, 8), 0, stream>>>(W1, BtA, BtB);
    k3_init_out<<<(NMENT * (MAXK + 1) + 255) / 256, 256, 0, stream>>>(faiss, nota, out);
    // K1: M[4096x768] = ment @ W1a + b1 : 16 t-tiles x 3 n-splits
    gemm_core<0><<<48, 1024, 0, stream>>>(ment, BtA, nullptr, nullptr, nullptr,
                                          nullptr, nullptr, b1, M);
    // K2: 512 t-tiles x 3 n-splits, XCD-grouped
    gemm_core<1><<<1536, 1024, 0, stream>>>(cand, BtB, M, W2, b2,
                                            mention_idx, col_idx, nullptr, out);
}